// Round 2
// baseline (185.516 us; speedup 1.0000x reference)
//
#include <hip/hip_runtime.h>

// WaveletLayer on [4096,4096] fp32:
//   out = diag_s * DWT3( diag_g * (DWT3(diag_b * x))[perm] )
// Haar DWT3 packet layout: [cA3(512) | cD3(512) | cD2(1024) | cD1(2048)].
//
// Block of 256 threads (4 waves). DWTs run fully in registers (thread owns
// 16 contiguous columns); LDS only for the permutation round-trip.
//
// v3: occupancy-first. v1 (double-buffered LDS, 1 barrier/row, R=4,
// grid=1024) ran at 26% occupancy — 4 blocks/CU, latency-bound (VALUBusy
// 7.6%, HBM 33%). v2 (LDS-only barrier + prefetch) regressed: per-wave
// pipelining isn't the issue, TLP is. So: SINGLE-buffered LDS (16 KB/block,
// 2 barriers/row), R=2, grid=2048 -> exactly 8 blocks/CU (LDS 128/160 KB,
// 32 waves/CU, VGPR fits 64). Barrier stalls of one block are covered by
// the other 7 resident blocks.

#define D   4096
#define NT  256            // 16 columns / thread
#define R   2              // rows per block -> grid 2048 = 8 blocks/CU

#define C_INV_SQRT2 0.70710678118654752440f

typedef float vf2 __attribute__((ext_vector_type(2)));
typedef float vf4 __attribute__((ext_vector_type(4)));

// XOR swizzle to break power-of-2 patterns on the scatter writes.
static __device__ __forceinline__ int swz(int i) {
    return i ^ ((i >> 5) & 31);
}

// 3 in-register Haar levels on 16 contiguous elements.
static __device__ __forceinline__ void dwt3_reg(const float v[16],
                                                float a3[2], float d3[2],
                                                float d2[4], float d1[8]) {
    float a1[8];
    #pragma unroll
    for (int j = 0; j < 8; ++j) {
        a1[j] = (v[2 * j] + v[2 * j + 1]) * C_INV_SQRT2;
        d1[j] = (v[2 * j] - v[2 * j + 1]) * C_INV_SQRT2;
    }
    float a2[4];
    #pragma unroll
    for (int j = 0; j < 4; ++j) {
        a2[j] = (a1[2 * j] + a1[2 * j + 1]) * C_INV_SQRT2;
        d2[j] = (a1[2 * j] - a1[2 * j + 1]) * C_INV_SQRT2;
    }
    #pragma unroll
    for (int j = 0; j < 2; ++j) {
        a3[j] = (a2[2 * j] + a2[2 * j + 1]) * C_INV_SQRT2;
        d3[j] = (a2[2 * j] - a2[2 * j + 1]) * C_INV_SQRT2;
    }
}

__global__ __launch_bounds__(NT, 8) void wavelet_rows_kernel(
    const float* __restrict__ x,
    const float* __restrict__ diag_s,
    const float* __restrict__ diag_g,
    const float* __restrict__ diag_b,
    const int*   __restrict__ perm,
    float*       __restrict__ out)
{
    __shared__ float buf[D];          // single buffer: 16 KB/block

    const int t = threadIdx.x;
    const size_t row0 = (size_t)blockIdx.x * R;

    // ---- load row-invariant tables into registers (once per block) ----
    float db[16], dg[16];
    int   pidx[16];
    {
        const vf4* b4 = (const vf4*)diag_b;
        const vf4* g4 = (const vf4*)diag_g;
        const int4* p4 = (const int4*)perm;
        #pragma unroll
        for (int k = 0; k < 4; ++k) {
            vf4 bv = b4[4 * t + k];
            db[4 * k + 0] = bv.x; db[4 * k + 1] = bv.y;
            db[4 * k + 2] = bv.z; db[4 * k + 3] = bv.w;
            vf4 gv = g4[4 * t + k];
            dg[4 * k + 0] = gv.x; dg[4 * k + 1] = gv.y;
            dg[4 * k + 2] = gv.z; dg[4 * k + 3] = gv.w;
            int4 pv = p4[4 * t + k];
            pidx[4 * k + 0] = pv.x; pidx[4 * k + 1] = pv.y;
            pidx[4 * k + 2] = pv.z; pidx[4 * k + 3] = pv.w;
        }
    }
    // diag_s at the thread-fixed packet store positions:
    vf2 sA, sD3;
    vf4 sD2, sD1a, sD1b;
    {
        const vf2* s2 = (const vf2*)diag_s;
        const vf4* s4 = (const vf4*)diag_s;
        sA   = s2[t];               // floats 2t, 2t+1      (cA3)
        sD3  = s2[256 + t];         // floats 512+2t..      (cD3)
        sD2  = s4[256 + t];         // floats 1024+4t..     (cD2)
        sD1a = s4[512 + 2 * t];     // floats 2048+8t..     (cD1)
        sD1b = s4[512 + 2 * t + 1];
    }

    // ---- row loop: scatter -> sync -> gather -> sync ----
    for (int r = 0; r < R; ++r) {
        const vf4* x4 = (const vf4*)(x + (row0 + r) * (size_t)D);

        // load 16 contiguous x, multiply diag_b
        float v[16];
        #pragma unroll
        for (int k = 0; k < 4; ++k) {
            vf4 xv = x4[4 * t + k];
            v[4 * k + 0] = xv.x * db[4 * k + 0];
            v[4 * k + 1] = xv.y * db[4 * k + 1];
            v[4 * k + 2] = xv.z * db[4 * k + 2];
            v[4 * k + 3] = xv.w * db[4 * k + 3];
        }

        // DWT #1 in registers
        float a3[2], d3[2], d2[4], d1[8];
        dwt3_reg(v, a3, d3, d2, d1);

        // scatter packet layout to LDS (swizzled)
        #pragma unroll
        for (int j = 0; j < 2; ++j) buf[swz(2 * t + j)]        = a3[j];
        #pragma unroll
        for (int j = 0; j < 2; ++j) buf[swz(512 + 2 * t + j)]  = d3[j];
        #pragma unroll
        for (int j = 0; j < 4; ++j) buf[swz(1024 + 4 * t + j)] = d2[j];
        #pragma unroll
        for (int j = 0; j < 8; ++j) buf[swz(2048 + 8 * t + j)] = d1[j];

        __syncthreads();

        // permutation gather * diag_g
        float w[16];
        #pragma unroll
        for (int k = 0; k < 16; ++k) {
            w[k] = buf[swz(pidx[k])] * dg[k];
        }

        // release the buffer for the next row's scatter; the gather's
        // ds_reads are drained by syncthreads' lgkmcnt(0), and the stores
        // below overlap the next row's load/DWT1 phase.
        if (r + 1 < R) __syncthreads();

        // DWT #2 in registers
        float b3[2], e3[2], e2[4], e1[8];
        dwt3_reg(w, b3, e3, e2, e1);

        // multiply diag_s, nontemporal coalesced store
        float* orow = out + (row0 + r) * (size_t)D;
        {
            vf2* o2 = (vf2*)orow;
            vf2 ov;
            ov.x = b3[0] * sA.x;  ov.y = b3[1] * sA.y;
            __builtin_nontemporal_store(ov, &o2[t]);
            ov.x = e3[0] * sD3.x; ov.y = e3[1] * sD3.y;
            __builtin_nontemporal_store(ov, &o2[256 + t]);

            vf4* o4 = (vf4*)orow;
            vf4 o;
            o.x = e2[0] * sD2.x; o.y = e2[1] * sD2.y;
            o.z = e2[2] * sD2.z; o.w = e2[3] * sD2.w;
            __builtin_nontemporal_store(o, &o4[256 + t]);
            o.x = e1[0] * sD1a.x; o.y = e1[1] * sD1a.y;
            o.z = e1[2] * sD1a.z; o.w = e1[3] * sD1a.w;
            __builtin_nontemporal_store(o, &o4[512 + 2 * t]);
            o.x = e1[4] * sD1b.x; o.y = e1[5] * sD1b.y;
            o.z = e1[6] * sD1b.z; o.w = e1[7] * sD1b.w;
            __builtin_nontemporal_store(o, &o4[512 + 2 * t + 1]);
        }
    }
}

extern "C" void kernel_launch(void* const* d_in, const int* in_sizes, int n_in,
                              void* d_out, int out_size, void* d_ws, size_t ws_size,
                              hipStream_t stream) {
    // setup_inputs() order: x, diag_s, diag_g, diag_b, dec_lo, dec_hi, perm, scales
    const float* x      = (const float*)d_in[0];
    const float* diag_s = (const float*)d_in[1];
    const float* diag_g = (const float*)d_in[2];
    const float* diag_b = (const float*)d_in[3];
    const int* perm     = (const int*)d_in[6];
    float* out          = (float*)d_out;

    const int B = 4096 / R;
    wavelet_rows_kernel<<<B, NT, 0, stream>>>(x, diag_s, diag_g, diag_b, perm, out);
}

// Round 3
// 126.821 us; speedup vs baseline: 1.4628x; 1.4628x over previous
//
#include <hip/hip_runtime.h>

// WaveletLayer on [4096,4096] fp32:
//   out = diag_s * DWT3( diag_g * (DWT3(diag_b * x))[perm] )
// Haar DWT3 packet layout: [cA3(512) | cD3(512) | cD2(1024) | cD1(2048)].
//
// Block of 256 threads (4 waves). DWTs run fully in registers (thread owns
// 16 contiguous columns); LDS only for the permutation round-trip.
//
// History:
//  v1: double-buffered LDS (32 KB), R=4, grid=1024 -> 26% occupancy,
//      latency-bound. 44 us/dispatch.
//  v2: LDS-only barrier + prefetch -> regressed (TLP, not per-wave
//      pipelining, is the limiter).
//  v3: single-buffer LDS (16 KB), R=2, grid=2048 (8 blocks/CU) raised
//      occupancy to 67% -- but __launch_bounds__(256,8) forced VGPR=32,
//      spilling the 60+-register working set to scratch: FETCH+WRITE
//      tripled, 90 us/dispatch.
//  v4 (this round): v3 structure, natural register budget
//      (__launch_bounds__(256) -> 64 VGPR like v1, no spill). 8 blocks/CU
//      by grid, 32 waves/CU, zero scratch.

#define D   4096
#define NT  256            // 16 columns / thread
#define R   2              // rows per block -> grid 2048 = 8 blocks/CU

#define C_INV_SQRT2 0.70710678118654752440f

typedef float vf2 __attribute__((ext_vector_type(2)));
typedef float vf4 __attribute__((ext_vector_type(4)));

// XOR swizzle to break power-of-2 patterns on the scatter writes.
static __device__ __forceinline__ int swz(int i) {
    return i ^ ((i >> 5) & 31);
}

// 3 in-register Haar levels on 16 contiguous elements.
static __device__ __forceinline__ void dwt3_reg(const float v[16],
                                                float a3[2], float d3[2],
                                                float d2[4], float d1[8]) {
    float a1[8];
    #pragma unroll
    for (int j = 0; j < 8; ++j) {
        a1[j] = (v[2 * j] + v[2 * j + 1]) * C_INV_SQRT2;
        d1[j] = (v[2 * j] - v[2 * j + 1]) * C_INV_SQRT2;
    }
    float a2[4];
    #pragma unroll
    for (int j = 0; j < 4; ++j) {
        a2[j] = (a1[2 * j] + a1[2 * j + 1]) * C_INV_SQRT2;
        d2[j] = (a1[2 * j] - a1[2 * j + 1]) * C_INV_SQRT2;
    }
    #pragma unroll
    for (int j = 0; j < 2; ++j) {
        a3[j] = (a2[2 * j] + a2[2 * j + 1]) * C_INV_SQRT2;
        d3[j] = (a2[2 * j] - a2[2 * j + 1]) * C_INV_SQRT2;
    }
}

__global__ __launch_bounds__(NT) void wavelet_rows_kernel(
    const float* __restrict__ x,
    const float* __restrict__ diag_s,
    const float* __restrict__ diag_g,
    const float* __restrict__ diag_b,
    const int*   __restrict__ perm,
    float*       __restrict__ out)
{
    __shared__ float buf[D];          // single buffer: 16 KB/block

    const int t = threadIdx.x;
    const size_t row0 = (size_t)blockIdx.x * R;

    // ---- load row-invariant tables into registers (once per block) ----
    float db[16], dg[16];
    int   pidx[16];
    {
        const vf4* b4 = (const vf4*)diag_b;
        const vf4* g4 = (const vf4*)diag_g;
        const int4* p4 = (const int4*)perm;
        #pragma unroll
        for (int k = 0; k < 4; ++k) {
            vf4 bv = b4[4 * t + k];
            db[4 * k + 0] = bv.x; db[4 * k + 1] = bv.y;
            db[4 * k + 2] = bv.z; db[4 * k + 3] = bv.w;
            vf4 gv = g4[4 * t + k];
            dg[4 * k + 0] = gv.x; dg[4 * k + 1] = gv.y;
            dg[4 * k + 2] = gv.z; dg[4 * k + 3] = gv.w;
            int4 pv = p4[4 * t + k];
            pidx[4 * k + 0] = pv.x; pidx[4 * k + 1] = pv.y;
            pidx[4 * k + 2] = pv.z; pidx[4 * k + 3] = pv.w;
        }
    }
    // diag_s at the thread-fixed packet store positions:
    vf2 sA, sD3;
    vf4 sD2, sD1a, sD1b;
    {
        const vf2* s2 = (const vf2*)diag_s;
        const vf4* s4 = (const vf4*)diag_s;
        sA   = s2[t];               // floats 2t, 2t+1      (cA3)
        sD3  = s2[256 + t];         // floats 512+2t..      (cD3)
        sD2  = s4[256 + t];         // floats 1024+4t..     (cD2)
        sD1a = s4[512 + 2 * t];     // floats 2048+8t..     (cD1)
        sD1b = s4[512 + 2 * t + 1];
    }

    // ---- row loop: scatter -> sync -> gather -> sync ----
    for (int r = 0; r < R; ++r) {
        const vf4* x4 = (const vf4*)(x + (row0 + r) * (size_t)D);

        // load 16 contiguous x, multiply diag_b
        float v[16];
        #pragma unroll
        for (int k = 0; k < 4; ++k) {
            vf4 xv = x4[4 * t + k];
            v[4 * k + 0] = xv.x * db[4 * k + 0];
            v[4 * k + 1] = xv.y * db[4 * k + 1];
            v[4 * k + 2] = xv.z * db[4 * k + 2];
            v[4 * k + 3] = xv.w * db[4 * k + 3];
        }

        // DWT #1 in registers
        float a3[2], d3[2], d2[4], d1[8];
        dwt3_reg(v, a3, d3, d2, d1);

        // scatter packet layout to LDS (swizzled)
        #pragma unroll
        for (int j = 0; j < 2; ++j) buf[swz(2 * t + j)]        = a3[j];
        #pragma unroll
        for (int j = 0; j < 2; ++j) buf[swz(512 + 2 * t + j)]  = d3[j];
        #pragma unroll
        for (int j = 0; j < 4; ++j) buf[swz(1024 + 4 * t + j)] = d2[j];
        #pragma unroll
        for (int j = 0; j < 8; ++j) buf[swz(2048 + 8 * t + j)] = d1[j];

        __syncthreads();

        // permutation gather * diag_g
        float w[16];
        #pragma unroll
        for (int k = 0; k < 16; ++k) {
            w[k] = buf[swz(pidx[k])] * dg[k];
        }

        // release the buffer for the next row's scatter; the gather's
        // ds_reads are drained by syncthreads' lgkmcnt(0), and the stores
        // below overlap the next row's load/DWT1 phase.
        if (r + 1 < R) __syncthreads();

        // DWT #2 in registers
        float b3[2], e3[2], e2[4], e1[8];
        dwt3_reg(w, b3, e3, e2, e1);

        // multiply diag_s, nontemporal coalesced store
        float* orow = out + (row0 + r) * (size_t)D;
        {
            vf2* o2 = (vf2*)orow;
            vf2 ov;
            ov.x = b3[0] * sA.x;  ov.y = b3[1] * sA.y;
            __builtin_nontemporal_store(ov, &o2[t]);
            ov.x = e3[0] * sD3.x; ov.y = e3[1] * sD3.y;
            __builtin_nontemporal_store(ov, &o2[256 + t]);

            vf4* o4 = (vf4*)orow;
            vf4 o;
            o.x = e2[0] * sD2.x; o.y = e2[1] * sD2.y;
            o.z = e2[2] * sD2.z; o.w = e2[3] * sD2.w;
            __builtin_nontemporal_store(o, &o4[256 + t]);
            o.x = e1[0] * sD1a.x; o.y = e1[1] * sD1a.y;
            o.z = e1[2] * sD1a.z; o.w = e1[3] * sD1a.w;
            __builtin_nontemporal_store(o, &o4[512 + 2 * t]);
            o.x = e1[4] * sD1b.x; o.y = e1[5] * sD1b.y;
            o.z = e1[6] * sD1b.z; o.w = e1[7] * sD1b.w;
            __builtin_nontemporal_store(o, &o4[512 + 2 * t + 1]);
        }
    }
}

extern "C" void kernel_launch(void* const* d_in, const int* in_sizes, int n_in,
                              void* d_out, int out_size, void* d_ws, size_t ws_size,
                              hipStream_t stream) {
    // setup_inputs() order: x, diag_s, diag_g, diag_b, dec_lo, dec_hi, perm, scales
    const float* x      = (const float*)d_in[0];
    const float* diag_s = (const float*)d_in[1];
    const float* diag_g = (const float*)d_in[2];
    const float* diag_b = (const float*)d_in[3];
    const int* perm     = (const int*)d_in[6];
    float* out          = (float*)d_out;

    const int B = 4096 / R;
    wavelet_rows_kernel<<<B, NT, 0, stream>>>(x, diag_s, diag_g, diag_b, perm, out);
}

// Round 4
// 125.999 us; speedup vs baseline: 1.4724x; 1.0065x over previous
//
#include <hip/hip_runtime.h>

// WaveletLayer on [4096,4096] fp32:
//   out = diag_s * DWT3( diag_g * (DWT3(diag_b * x))[perm] )
// Haar DWT3 packet layout: [cA3(512) | cD3(512) | cD2(1024) | cD1(2048)].
//
// History:
//  v1: 16-contiguous-cols/thread, reg tables, dbuf LDS, R=4. 44 us.
//  v2: LDS-only barrier + prefetch -> regressed (traffic up).
//  v3: R=2 + launch_bounds(256,8) -> VGPR=32 spills, 90 us.
//  v4: R=2, natural regs (68 VGPR) -> 4-wave bucket again, 44 us == v1.
//  v5 (this round): EVERY global access in v1-v4 was strided
//      (lane t at byte 64t+16k: 16B used per 64B line, 4x L1 transactions).
//      Re-map ownership to 4 chunks of 4 contiguous columns per thread
//      (chunk k = cols 1024k+4t..+3, load x4[256k+t] -> lane-contiguous).
//      Haar L1/L2 are chunk-local; L3 via one __shfl_xor(a2,1) per chunk
//      (even lane -> cA3, odd lane -> cD3). Tables load coalesced the same
//      way. Scatter/store positions become lane-contiguous (swz dropped).

#define D   4096
#define NT  256            // 4 chunks x 4 columns per thread
#define R   2              // rows per block -> grid 2048

#define C_INV_SQRT2 0.70710678118654752440f

typedef float vf2 __attribute__((ext_vector_type(2)));
typedef float vf4 __attribute__((ext_vector_type(4)));

// One Haar chunk: 4 contiguous columns -> d1 pair, d2, and level-3 value
// (even lane: cA3, odd lane: cD3) via cross-lane pairing of a2.
static __device__ __forceinline__ void haar_chunk(
    float v0, float v1, float v2, float v3, int odd,
    float& d1a, float& d1b, float& d2v, float& l3)
{
    float a10 = (v0 + v1) * C_INV_SQRT2;
    d1a       = (v0 - v1) * C_INV_SQRT2;
    float a11 = (v2 + v3) * C_INV_SQRT2;
    d1b       = (v2 - v3) * C_INV_SQRT2;
    float a2  = (a10 + a11) * C_INV_SQRT2;
    d2v       = (a10 - a11) * C_INV_SQRT2;
    float a2p = __shfl_xor(a2, 1);              // neighbor's a2 (lane t^1)
    // even lane holds a2[2m], partner a2[2m+1]:  a3 = (a2 + a2p)*c
    // odd  lane holds a2[2m+1], partner a2[2m]:  d3 = (a2p - a2)*c
    l3 = (odd ? (a2p - a2) : (a2 + a2p)) * C_INV_SQRT2;
}

__global__ __launch_bounds__(NT) void wavelet_rows_kernel(
    const float* __restrict__ x,
    const float* __restrict__ diag_s,
    const float* __restrict__ diag_g,
    const float* __restrict__ diag_b,
    const int*   __restrict__ perm,
    float*       __restrict__ out)
{
    __shared__ float buf[D];          // single packet buffer: 16 KB/block

    const int t   = threadIdx.x;
    const int s   = t >> 1;           // lane-pair index
    const int odd = t & 1;
    const size_t row0 = (size_t)blockIdx.x * R;

    // ---- row-invariant tables, ALL coalesced (lane-contiguous) ----
    // chunk k covers columns 1024k + 4t .. +3
    vf4  db[4], dg[4];
    int4 pidx[4];
    vf2  sd1[4];                      // diag_s for the cD1 store pair
    float sd2[4], sl3[4];             // diag_s for cD2 / (cA3|cD3) stores
    {
        const vf4* b4 = (const vf4*)diag_b;
        const vf4* g4 = (const vf4*)diag_g;
        const int4* p4 = (const int4*)perm;
        const vf2* s2 = (const vf2*)diag_s;
        #pragma unroll
        for (int k = 0; k < 4; ++k) {
            db[k]   = b4[256 * k + t];
            dg[k]   = g4[256 * k + t];
            pidx[k] = p4[256 * k + t];
            sd1[k]  = s2[1024 + 256 * k + t];              // floats 2048+512k+2t..
            sd2[k]  = diag_s[1024 + 256 * k + t];
            sl3[k]  = diag_s[(odd ? 512 : 0) + 128 * k + s];
        }
    }

    // ---- row loop: scatter -> sync -> gather -> sync ----
    for (int r = 0; r < R; ++r) {
        const vf4* x4 = (const vf4*)(x + (row0 + r) * (size_t)D);

        // DWT #1 per chunk, scatter packet to LDS (lane-contiguous banks)
        #pragma unroll
        for (int k = 0; k < 4; ++k) {
            vf4 xv = x4[256 * k + t];                      // coalesced 16B/lane
            float d1a, d1b, d2v, l3;
            haar_chunk(xv.x * db[k].x, xv.y * db[k].y,
                       xv.z * db[k].z, xv.w * db[k].w, odd,
                       d1a, d1b, d2v, l3);
            vf2 dp; dp.x = d1a; dp.y = d1b;
            *(vf2*)&buf[2048 + 512 * k + 2 * t] = dp;      // cD1 pair
            buf[1024 + 256 * k + t] = d2v;                 // cD2
            buf[(odd ? 512 : 0) + 128 * k + s] = l3;       // cA3 | cD3
        }

        __syncthreads();

        // permutation gather * diag_g, DWT #2 per chunk, diag_s, NT store
        float* orow = out + (row0 + r) * (size_t)D;
        #pragma unroll
        for (int k = 0; k < 4; ++k) {
            float w0 = buf[pidx[k].x] * dg[k].x;
            float w1 = buf[pidx[k].y] * dg[k].y;
            float w2 = buf[pidx[k].z] * dg[k].z;
            float w3 = buf[pidx[k].w] * dg[k].w;
            float e1a, e1b, e2v, f3;
            haar_chunk(w0, w1, w2, w3, odd, e1a, e1b, e2v, f3);

            vf2 ep; ep.x = e1a * sd1[k].x; ep.y = e1b * sd1[k].y;
            __builtin_nontemporal_store(ep, &((vf2*)orow)[1024 + 256 * k + t]);
            __builtin_nontemporal_store(e2v * sd2[k],
                                        &orow[1024 + 256 * k + t]);
            __builtin_nontemporal_store(f3 * sl3[k],
                                        &orow[(odd ? 512 : 0) + 128 * k + s]);
        }

        // release buf for next row's scatter (gather reads are drained by
        // syncthreads' lgkmcnt(0); NT stores overlap next row's loads).
        if (r + 1 < R) __syncthreads();
    }
}

extern "C" void kernel_launch(void* const* d_in, const int* in_sizes, int n_in,
                              void* d_out, int out_size, void* d_ws, size_t ws_size,
                              hipStream_t stream) {
    // setup_inputs() order: x, diag_s, diag_g, diag_b, dec_lo, dec_hi, perm, scales
    const float* x      = (const float*)d_in[0];
    const float* diag_s = (const float*)d_in[1];
    const float* diag_g = (const float*)d_in[2];
    const float* diag_b = (const float*)d_in[3];
    const int* perm     = (const int*)d_in[6];
    float* out          = (float*)d_out;

    const int B = 4096 / R;
    wavelet_rows_kernel<<<B, NT, 0, stream>>>(x, diag_s, diag_g, diag_b, perm, out);
}